// Round 4
// baseline (156.195 us; speedup 1.0000x reference)
//
#include <hip/hip_runtime.h>
#include <hip/hip_bf16.h>

// SimCLR loss, fused single-pass kernel. B=128, T=256, F=512, N=2B=256.
// tau=0.5 -> sim*2. One block per t (grid=256 = CU count), 512 threads.
// Single column pass: each staged [256 rows][64 k] bf16 tile (XOR-swizzled,
// double-buffered, T14 issue-early/write-late) feeds BOTH the A-rows and the
// full 256 B-cols; wave tile 64x128, acc[4][8] = 128 VGPR (irreducible).
// Row norms come free from the gram DIAGONAL (sim[r][r] = ||z_r||^2,
// bf16-consistent with the numerator) -> rsqrt scaling in epilogue.
// No-max logsumexp (|s| <= ~2.05). One global atomicAdd per block.

#define Bc 128
#define Tc 256
#define Fc 512
#define Nc 256
#define BK 64

typedef __bf16 bf16x8 __attribute__((ext_vector_type(8)));
typedef float f32x4 __attribute__((ext_vector_type(4)));

__global__ __launch_bounds__(512, 2)
void simclr_fused(const float* __restrict__ zi, const float* __restrict__ zj,
                  float* __restrict__ out) {
  const int t    = blockIdx.x;
  const int tid  = threadIdx.x;
  const int lane = tid & 63;
  const int wid  = tid >> 6;
  const int wr   = wid & 3;   // 4 row-waves  -> 64 rows each
  const int wc   = wid >> 2;  // 2 col-waves  -> 128 cols each

  __shared__ __align__(16) __bf16 tile[2][Nc * BK];  // 2 x 32 KB, swizzled
  __shared__ float rowssq[Nc];
  __shared__ float invn[Nc];
  __shared__ float rowsum[Nc];
  __shared__ float posv[Nc];
  __shared__ float wsum[8];

  if (tid < Nc) rowsum[tid] = 0.f;
  __syncthreads();

  // Staging ownership: g = tid + j*512, row = g>>3 (0..255), s = g&7
  // (32B fp32 chunk within the 256B k-tile row -> 16B bf16 slot in LDS).
  const float* srow[4];
  int ssl[4], wof[4];
#pragma unroll
  for (int j = 0; j < 4; ++j) {
    int g   = tid + j * 512;
    int row = g >> 3;
    int s   = g & 7;
    ssl[j]  = s;
    wof[j]  = (row << 6) + ((s ^ (row & 7)) << 3);  // swizzled LDS offset (bf16 elems)
    srow[j] = (row < Bc) ? (zi + ((size_t)row * Tc + t) * Fc)
                         : (zj + ((size_t)(row - Bc) * Tc + t) * Fc);
  }

  f32x4 acc[4][8];
#pragma unroll
  for (int m = 0; m < 4; ++m)
#pragma unroll
    for (int n = 0; n < 8; ++n)
      acc[m][n] = (f32x4){0.f, 0.f, 0.f, 0.f};

  float4 ra[4], rb[4];  // in-flight staging registers (issue-early)

  auto LOADR = [&](int kt) {  // issue global loads into registers
#pragma unroll
    for (int j = 0; j < 4; ++j) {
      const float4* p = reinterpret_cast<const float4*>(srow[j] + kt * BK + ssl[j] * 8);
      ra[j] = p[0];
      rb[j] = p[1];
    }
  };
  auto WRITE = [&](int b) {  // consume regs: cvt + swizzled ds_write
#pragma unroll
    for (int j = 0; j < 4; ++j) {
      bf16x8 v;
      v[0]=(__bf16)ra[j].x; v[1]=(__bf16)ra[j].y; v[2]=(__bf16)ra[j].z; v[3]=(__bf16)ra[j].w;
      v[4]=(__bf16)rb[j].x; v[5]=(__bf16)rb[j].y; v[6]=(__bf16)rb[j].z; v[7]=(__bf16)rb[j].w;
      *reinterpret_cast<bf16x8*>(&tile[b][wof[j]]) = v;
    }
  };

  // prologue: stage k-tile 0 into buffer 0
  LOADR(0);
  WRITE(0);

  for (int kt = 0; kt < 8; ++kt) {
    __syncthreads();               // tile[kt&1] writes now visible
    if (kt < 7) LOADR(kt + 1);     // loads in flight under the MFMA phase
    const __bf16* tb = tile[kt & 1];
#pragma unroll
    for (int kk = 0; kk < 2; ++kk) {
      const int kslot = (kk << 2) + (lane >> 4);  // 16B slot index along k
      bf16x8 bfrag[8];
#pragma unroll
      for (int n = 0; n < 8; ++n) {
        int c  = (wc << 7) + (n << 4) + (lane & 15);  // gram col = LDS row
        int sw = kslot ^ (c & 7);
        bfrag[n] = *reinterpret_cast<const bf16x8*>(&tb[(c << 6) + (sw << 3)]);
      }
#pragma unroll
      for (int m = 0; m < 4; ++m) {
        int r  = (wr << 6) + (m << 4) + (lane & 15);
        int sw = kslot ^ (r & 7);
        bf16x8 afrag = *reinterpret_cast<const bf16x8*>(&tb[(r << 6) + (sw << 3)]);
#pragma unroll
        for (int n = 0; n < 8; ++n)
          acc[m][n] = __builtin_amdgcn_mfma_f32_16x16x32_bf16(afrag, bfrag[n],
                                                              acc[m][n], 0, 0, 0);
      }
    }
    if (kt < 7) WRITE((kt + 1) & 1);  // write-late: after MFMAs
  }

  // Epilogue pass 1: squared norms = gram diagonal (exactly one owner per r).
  // C/D layout: col = lane&15, row = (lane>>4)*4 + q [m89-verified].
#pragma unroll
  for (int m = 0; m < 4; ++m)
#pragma unroll
    for (int q = 0; q < 4; ++q) {
      int r = (wr << 6) + (m << 4) + ((lane >> 4) << 2) + q;
#pragma unroll
      for (int n = 0; n < 8; ++n) {
        int c = (wc << 7) + (n << 4) + (lane & 15);
        if (c == r) rowssq[r] = acc[m][n][q];
      }
    }
  __syncthreads();
  if (tid < Nc) invn[tid] = 1.0f / fmaxf(sqrtf(rowssq[tid]), 1e-8f);
  __syncthreads();

  // Epilogue pass 2: scale, exp, masked row-sum, positive extraction.
  // (A full D-transpose would be benign: gram + mask + pos-set symmetric.)
#pragma unroll
  for (int m = 0; m < 4; ++m) {
#pragma unroll
    for (int q = 0; q < 4; ++q) {
      int r = (wr << 6) + (m << 4) + ((lane >> 4) << 2) + q;
      float inr = invn[r];
      float partial = 0.f;
#pragma unroll
      for (int n = 0; n < 8; ++n) {
        int c = (wc << 7) + (n << 4) + (lane & 15);
        float s = acc[m][n][q] * inr * invn[c] * 2.0f;  // 1/tau = 2
        if (c == (r ^ Bc)) posv[r] = s;   // positive pair: one writer per row
        if (c != r) partial += __expf(s); // diagonal excluded
      }
      partial += __shfl_xor(partial, 1);
      partial += __shfl_xor(partial, 2);
      partial += __shfl_xor(partial, 4);
      partial += __shfl_xor(partial, 8);
      if ((lane & 15) == 0) atomicAdd(&rowsum[r], partial);
    }
  }

  __syncthreads();
  float v = 0.f;
  if (tid < Nc) v = __logf(rowsum[tid]) - posv[tid];
#pragma unroll
  for (int off = 32; off > 0; off >>= 1) v += __shfl_down(v, off);
  if (lane == 0) wsum[wid] = v;
  __syncthreads();
  if (tid == 0) {
    float sum = 0.f;
#pragma unroll
    for (int i = 0; i < 8; ++i) sum += wsum[i];
    atomicAdd(out, sum * (1.0f / 65536.0f));  // /(T*N)
  }
}

extern "C" void kernel_launch(void* const* d_in, const int* in_sizes, int n_in,
                              void* d_out, int out_size, void* d_ws, size_t ws_size,
                              hipStream_t stream) {
  const float* zi = (const float*)d_in[0];
  const float* zj = (const float*)d_in[1];
  float* out = (float*)d_out;
  hipMemsetAsync(out, 0, sizeof(float) * out_size, stream);
  simclr_fused<<<Tc, 512, 0, stream>>>(zi, zj, out);
}

// Round 6
// 152.609 us; speedup vs baseline: 1.0235x; 1.0235x over previous
//
#include <hip/hip_runtime.h>
#include <hip/hip_bf16.h>

// SimCLR loss, fused single-pass kernel. B=128, T=256, F=512, N=2B=256.
// tau=0.5 -> sim*2. One 1024-thread block per t (grid=256), 16 waves = 4/SIMD
// for latency hiding (__launch_bounds__(1024,4) caps unified regs at 128 so
// the full block is resident; acc[4][4]=64 is the irreducible per-thread
// output share). Staged [256 rows][64 k] bf16 tiles (XOR-swizzled, double-
// buffered, issue-early/write-late). Coalesced staging: each
// global_load_dwordx4 instruction covers 4 complete rows x 256B; LDS writes
// are 8B, 16 lanes span one full 128B row = every bank once. Row norms from
// the gram DIAGONAL (bf16-consistent cosine) -> rsqrt in epilogue. No-max
// logsumexp (|s| <= ~2.05). One global atomicAdd per block.

#define Bc 128
#define Tc 256
#define Fc 512
#define Nc 256
#define BK 64
#define NW 16

typedef __bf16 bf16x8 __attribute__((ext_vector_type(8)));
typedef __bf16 bf16x4 __attribute__((ext_vector_type(4)));
typedef float f32x4 __attribute__((ext_vector_type(4)));

__global__ __launch_bounds__(1024, 4)
void simclr_fused(const float* __restrict__ zi, const float* __restrict__ zj,
                  float* __restrict__ out) {
  const int t    = blockIdx.x;
  const int tid  = threadIdx.x;
  const int lane = tid & 63;
  const int wid  = tid >> 6;   // 0..15
  const int wr   = wid & 3;    // 4 row-waves  -> 64 rows each
  const int wc   = wid >> 2;   // 4 col-waves  -> 64 cols each

  __shared__ __align__(16) __bf16 tile[2][Nc * BK];  // 2 x 32 KB, swizzled
  __shared__ float rowssq[Nc];
  __shared__ float invn[Nc];
  __shared__ float rowsum[Nc];
  __shared__ float posv[Nc];
  __shared__ float wsum[NW];

  if (tid < Nc) rowsum[tid] = 0.f;

  // Staging: load j covers rows wid*16 + j*4 .. +3 (row = .. + (lane>>4));
  // lane&15 selects the 16B piece -> one instruction = 4 full rows x 256B.
  const float* sp[4];
#pragma unroll
  for (int j = 0; j < 4; ++j) {
    int row = (wid << 4) + (j << 2) + (lane >> 4);
    const float* base = (row < Bc) ? (zi + ((size_t)row * Tc + t) * Fc)
                                   : (zj + ((size_t)(row - Bc) * Tc + t) * Fc);
    sp[j] = base + ((lane & 15) << 2);  // this lane's 4 floats
  }
  // Swizzled LDS byte offsets: wof[j] = wof[j&1] + (j>>1)*1024 because
  // (row+8)&7 == row&7 (j and j+2 differ by 8 rows) -> only 2 live regs.
  int wof2[2];
#pragma unroll
  for (int j = 0; j < 2; ++j) {
    int row = (wid << 4) + (j << 2) + (lane >> 4);
    int s = (lane & 15) >> 1;  // 16B bf16 slot (0..7)
    wof2[j] = (row << 7) + (((s ^ (row & 7)) << 4) | ((lane & 1) << 3));
  }

  f32x4 acc[4][4];
#pragma unroll
  for (int m = 0; m < 4; ++m)
#pragma unroll
    for (int n = 0; n < 4; ++n)
      acc[m][n] = (f32x4){0.f, 0.f, 0.f, 0.f};

  float4 ra[4];  // in-flight staging registers

  auto LOADR = [&](int kt) {
#pragma unroll
    for (int j = 0; j < 4; ++j)
      ra[j] = *reinterpret_cast<const float4*>(sp[j] + kt * BK);
  };
  auto WRITE = [&](int b) {  // cvt fp32->bf16 + swizzled 8B LDS store
    char* tb = (char*)&tile[b][0];
#pragma unroll
    for (int j = 0; j < 4; ++j) {
      bf16x4 v;
      v[0] = (__bf16)ra[j].x; v[1] = (__bf16)ra[j].y;
      v[2] = (__bf16)ra[j].z; v[3] = (__bf16)ra[j].w;
      *reinterpret_cast<bf16x4*>(tb + wof2[j & 1] + (j >> 1) * 1024) = v;
    }
  };

  __syncthreads();  // rowsum init visible
  LOADR(0);
  WRITE(0);

  for (int kt = 0; kt < 8; ++kt) {
    __syncthreads();               // tile[kt&1] writes visible
    if (kt < 7) LOADR(kt + 1);     // loads in flight under the MFMA phase
    const char* tb = (const char*)&tile[kt & 1][0];
#pragma unroll
    for (int kk = 0; kk < 2; ++kk) {
      // LDS row&7 == lane&7 for both frags -> shared swizzled k-slot
      const int sws = ((kk << 2) + (lane >> 4)) ^ (lane & 7);
      const char* ab = tb + ((((wr << 6) + (lane & 15)) << 7) + (sws << 4));
      const char* bb = tb + ((((wc << 6) + (lane & 15)) << 7) + (sws << 4));
      bf16x8 bf[4];
#pragma unroll
      for (int n = 0; n < 4; ++n)
        bf[n] = *reinterpret_cast<const bf16x8*>(bb + (n << 11));
#pragma unroll
      for (int m = 0; m < 4; ++m) {
        bf16x8 af = *reinterpret_cast<const bf16x8*>(ab + (m << 11));
#pragma unroll
        for (int n = 0; n < 4; ++n)
          acc[m][n] = __builtin_amdgcn_mfma_f32_16x16x32_bf16(af, bf[n],
                                                              acc[m][n], 0, 0, 0);
      }
    }
    if (kt < 7) WRITE((kt + 1) & 1);  // write-late: after MFMAs
  }

  // Epilogue pass 1: squared norms = gram diagonal (one owner per r:
  // waves with wr == wc). C/D layout: col = lane&15, row = (lane>>4)*4 + q.
#pragma unroll
  for (int m = 0; m < 4; ++m)
#pragma unroll
    for (int q = 0; q < 4; ++q) {
      int r = (wr << 6) + (m << 4) + ((lane >> 4) << 2) + q;
#pragma unroll
      for (int n = 0; n < 4; ++n) {
        int c = (wc << 6) + (n << 4) + (lane & 15);
        if (c == r) rowssq[r] = acc[m][n][q];
      }
    }
  __syncthreads();
  if (tid < Nc) invn[tid] = 1.0f / fmaxf(sqrtf(rowssq[tid]), 1e-8f);
  __syncthreads();

  // Epilogue pass 2: scale, exp, masked row-sum, positive extraction.
#pragma unroll
  for (int m = 0; m < 4; ++m) {
#pragma unroll
    for (int q = 0; q < 4; ++q) {
      int r = (wr << 6) + (m << 4) + ((lane >> 4) << 2) + q;
      float inr = invn[r];
      float partial = 0.f;
#pragma unroll
      for (int n = 0; n < 4; ++n) {
        int c = (wc << 6) + (n << 4) + (lane & 15);
        float s = acc[m][n][q] * inr * invn[c] * 2.0f;  // 1/tau = 2
        if (c == (r ^ Bc)) posv[r] = s;   // positive pair: one writer per row
        if (c != r) partial += __expf(s); // diagonal excluded
      }
      partial += __shfl_xor(partial, 1);
      partial += __shfl_xor(partial, 2);
      partial += __shfl_xor(partial, 4);
      partial += __shfl_xor(partial, 8);
      if ((lane & 15) == 0) atomicAdd(&rowsum[r], partial);
    }
  }

  __syncthreads();
  float v = 0.f;
  if (tid < Nc) v = __logf(rowsum[tid]) - posv[tid];
#pragma unroll
  for (int off = 32; off > 0; off >>= 1) v += __shfl_down(v, off);
  if (lane == 0) wsum[wid] = v;
  __syncthreads();
  if (tid == 0) {
    float sum = 0.f;
#pragma unroll
    for (int i = 0; i < NW; ++i) sum += wsum[i];
    atomicAdd(out, sum * (1.0f / 65536.0f));  // /(T*N)
  }
}

extern "C" void kernel_launch(void* const* d_in, const int* in_sizes, int n_in,
                              void* d_out, int out_size, void* d_ws, size_t ws_size,
                              hipStream_t stream) {
  const float* zi = (const float*)d_in[0];
  const float* zj = (const float*)d_in[1];
  float* out = (float*)d_out;
  hipMemsetAsync(out, 0, sizeof(float) * out_size, stream);
  simclr_fused<<<Tc, 1024, 0, stream>>>(zi, zj, out);
}